// Round 2
// baseline (510.388 us; speedup 1.0000x reference)
//
#include <hip/hip_runtime.h>
#include <stdint.h>

#define DIM 128
#define HIDDEN 512
#define EPS 1e-5f
#define HC 32               // hidden chunk
#define NCHUNK (HIDDEN/HC)  // 16
#define MT 2                // m-tiles (16 tokens each) per wave -> 32 tokens/wave

typedef __attribute__((ext_vector_type(8))) short bf16x8;
typedef __attribute__((ext_vector_type(4))) float f32x4;

__device__ __forceinline__ unsigned short bf16_rn(float f) {
    unsigned u = __builtin_bit_cast(unsigned, f);
    unsigned r = u + 0x7FFFu + ((u >> 16) & 1u);
    return (unsigned short)(r >> 16);
}
__device__ __forceinline__ float bf16_f32(unsigned short h) {
    unsigned u = ((unsigned)h) << 16;
    return __builtin_bit_cast(float, u);
}

// ---------------------------------------------------------------------------
// Prep: split w1 (512x128) and w2 (128x512) into hi/lo bf16 planes laid out in
// MFMA A-operand fragment order: value(frag fi, lane l, j) = W[t*16+(l&15)][ks*32+(l>>4)*8+j]
// w1f: fi = (p*32 + nt)*4 + ks   (nt: 32 hidden tiles, ks: 4 k-steps over DIM)
// w2f: fi = (p*8  + dt)*16 + ks  (dt: 8 out tiles,    ks: 16 k-steps over HIDDEN)
// ---------------------------------------------------------------------------
__global__ __launch_bounds__(256) void prep_weights(
    const float* __restrict__ w1, const float* __restrict__ w2,
    unsigned short* __restrict__ w1f, unsigned short* __restrict__ w2f) {
    int idx = blockIdx.x * 256 + threadIdx.x;   // 0 .. 262143
    int o = idx & 131071;
    int j = o & 7;
    int l = (o >> 3) & 63;
    int fi = o >> 9;
    if (idx < 131072) {
        int ks = fi & 3, t = (fi >> 2) & 31, p = fi >> 7;
        int row = t * 16 + (l & 15);
        int col = ks * 32 + (l >> 4) * 8 + j;
        float v = w1[row * DIM + col];
        unsigned short hi = bf16_rn(v);
        w1f[o] = p ? bf16_rn(v - bf16_f32(hi)) : hi;
    } else {
        int ks = fi & 15, t = (fi >> 4) & 7, p = fi >> 7;
        int row = t * 16 + (l & 15);
        int col = ks * 32 + (l >> 4) * 8 + j;
        float v = w2[row * HIDDEN + col];
        unsigned short hi = bf16_rn(v);
        w2f[o] = p ? bf16_rn(v - bf16_f32(hi)) : hi;
    }
}

// ---------------------------------------------------------------------------
// Fused LN -> Linear -> ReLU -> Linear. 4 waves/block, each wave owns 32
// tokens end-to-end. No inter-wave communication; no __syncthreads.
// Both GEMMs computed transposed (weights as MFMA A-operand):
//   G1: D[n][m] = sum_k w1[n][k]*xn[m][k]   (acc col = token)
//   G2: D[d][m] = sum_k w2[d][k]*h[m][k]    (lane's 4 regs = 4 consecutive d)
// ---------------------------------------------------------------------------
__global__ __launch_bounds__(256, 2) void fused_mlp(
    const float* __restrict__ x,
    const unsigned short* __restrict__ w1f,
    const unsigned short* __restrict__ w2f,
    const float* __restrict__ b1, const float* __restrict__ b2,
    const float* __restrict__ wn, const float* __restrict__ bn,
    float* __restrict__ out) {

    __shared__ __align__(16) char smem_all[4 * 8192];
    const int tid  = threadIdx.x;
    const int wid  = tid >> 6;
    const int lane = tid & 63;
    const int g    = lane >> 4;    // k-group 0..3
    const int li   = lane & 15;
    char* smem = smem_all + wid * 8192;

    const int tok_base = blockIdx.x * 128 + wid * 32;

    // per-lane LN affine params (cols 2*lane, 2*lane+1), loaded once
    float2 wnv = *(const float2*)(wn + lane * 2);
    float2 bnv = *(const float2*)(bn + lane * 2);

    // A(xn) fragments for GEMM1, kept in registers the whole kernel:
    // [mt][ks][plane] -> 64 VGPRs
    bf16x8 xf[MT][4][2];

    // ---- Phase 1: LayerNorm + split + transpose (via wave-private LDS bounce)
    for (int mt = 0; mt < MT; ++mt) {
        for (int r = 0; r < 16; ++r) {
            int tok = tok_base + mt * 16 + r;
            float2 xv = *(const float2*)(x + (size_t)tok * DIM + lane * 2);
            float s = xv.x + xv.y;
            float q = xv.x * xv.x + xv.y * xv.y;
            #pragma unroll
            for (int off = 32; off > 0; off >>= 1) {
                s += __shfl_xor(s, off, 64);
                q += __shfl_xor(q, off, 64);
            }
            float mean = s * (1.0f / 128.0f);
            float var  = q * (1.0f / 128.0f) - mean * mean;
            float rstd = rsqrtf(var + EPS);
            float y0 = (xv.x - mean) * rstd * wnv.x + bnv.x;
            float y1 = (xv.y - mean) * rstd * wnv.y + bnv.y;
            unsigned short h0 = bf16_rn(y0), h1 = bf16_rn(y1);
            unsigned short l0 = bf16_rn(y0 - bf16_f32(h0));
            unsigned short l1 = bf16_rn(y1 - bf16_f32(h1));
            unsigned hiw = (unsigned)h0 | ((unsigned)h1 << 16);
            unsigned low = (unsigned)l0 | ((unsigned)l1 << 16);
            // bounce tile [16][128] bf16 per plane, XOR-swizzled rows
            int byte = (r * 256 + lane * 4) ^ ((r & 7) << 4);
            *(unsigned*)(smem + byte)        = hiw;
            *(unsigned*)(smem + 4096 + byte) = low;
        }
        #pragma unroll
        for (int ks = 0; ks < 4; ++ks) {
            #pragma unroll
            for (int p = 0; p < 2; ++p) {
                int byte = (li * 256 + ks * 64 + g * 16) ^ ((li & 7) << 4);
                xf[mt][ks][p] = *(const bf16x8*)(smem + p * 4096 + byte);
            }
        }
    }

    // ---- Phase 2: chunk loop over hidden (16 chunks of 32)
    f32x4 acc2[8][MT];
    #pragma unroll
    for (int dt = 0; dt < 8; ++dt)
        #pragma unroll
        for (int mt = 0; mt < MT; ++mt)
            acc2[dt][mt] = (f32x4){0.f, 0.f, 0.f, 0.f};

    for (int c = 0; c < NCHUNK; ++c) {
        // --- GEMM1 (3-pass split) + bias + ReLU + split-store h
        #pragma unroll
        for (int ntl = 0; ntl < 2; ++ntl) {
            bf16x8 wfr[4][2];
            int ntg = c * 2 + ntl;
            #pragma unroll
            for (int ks = 0; ks < 4; ++ks) {
                #pragma unroll
                for (int p = 0; p < 2; ++p) {
                    size_t off = ((size_t)((p * 32 + ntg) * 4 + ks)) * 512 + lane * 8;
                    wfr[ks][p] = *(const bf16x8*)(w1f + off);
                }
            }
            f32x4 acc1[MT];
            #pragma unroll
            for (int mt = 0; mt < MT; ++mt) acc1[mt] = (f32x4){0.f, 0.f, 0.f, 0.f};
            #pragma unroll
            for (int ks = 0; ks < 4; ++ks) {
                #pragma unroll
                for (int mt = 0; mt < MT; ++mt) {
                    acc1[mt] = __builtin_amdgcn_mfma_f32_16x16x32_bf16(wfr[ks][0], xf[mt][ks][0], acc1[mt], 0, 0, 0);
                    acc1[mt] = __builtin_amdgcn_mfma_f32_16x16x32_bf16(wfr[ks][0], xf[mt][ks][1], acc1[mt], 0, 0, 0);
                    acc1[mt] = __builtin_amdgcn_mfma_f32_16x16x32_bf16(wfr[ks][1], xf[mt][ks][0], acc1[mt], 0, 0, 0);
                }
            }
            f32x4 b1v = *(const f32x4*)(b1 + c * HC + ntl * 16 + g * 4);
            #pragma unroll
            for (int mt = 0; mt < MT; ++mt) {
                unsigned hw[2], lw[2];
                #pragma unroll
                for (int rr = 0; rr < 2; ++rr) {
                    float v0 = fmaxf(acc1[mt][rr * 2]     + b1v[rr * 2],     0.f);
                    float v1 = fmaxf(acc1[mt][rr * 2 + 1] + b1v[rr * 2 + 1], 0.f);
                    unsigned short h0 = bf16_rn(v0), h1 = bf16_rn(v1);
                    unsigned short s0 = bf16_rn(v0 - bf16_f32(h0));
                    unsigned short s1 = bf16_rn(v1 - bf16_f32(h1));
                    hw[rr] = (unsigned)h0 | ((unsigned)h1 << 16);
                    lw[rr] = (unsigned)s0 | ((unsigned)s1 << 16);
                }
                // h tile [32][HC] bf16 per plane; lane writes 4 consecutive k
                int row  = mt * 16 + li;
                int byte = (row * 64 + ntl * 32 + g * 8) ^ (((row >> 1) & 3) << 4);
                *(uint2*)(smem + byte)        = make_uint2(hw[0], hw[1]);
                *(uint2*)(smem + 2048 + byte) = make_uint2(lw[0], lw[1]);
            }
        }
        // --- read h fragments (B-operand of GEMM2)
        bf16x8 hf[MT][2];
        #pragma unroll
        for (int mt = 0; mt < MT; ++mt) {
            #pragma unroll
            for (int p = 0; p < 2; ++p) {
                int row  = mt * 16 + li;
                int byte = (row * 64 + g * 16) ^ (((row >> 1) & 3) << 4);
                hf[mt][p] = *(const bf16x8*)(smem + p * 2048 + byte);
            }
        }
        // --- GEMM2 (3-pass split), accumulate C2^T
        #pragma unroll
        for (int dt = 0; dt < 8; ++dt) {
            size_t off0 = ((size_t)((0 * 8 + dt) * 16 + c)) * 512 + lane * 8;
            size_t off1 = ((size_t)((1 * 8 + dt) * 16 + c)) * 512 + lane * 8;
            bf16x8 w2hi = *(const bf16x8*)(w2f + off0);
            bf16x8 w2lo = *(const bf16x8*)(w2f + off1);
            #pragma unroll
            for (int mt = 0; mt < MT; ++mt) {
                acc2[dt][mt] = __builtin_amdgcn_mfma_f32_16x16x32_bf16(w2hi, hf[mt][0], acc2[dt][mt], 0, 0, 0);
                acc2[dt][mt] = __builtin_amdgcn_mfma_f32_16x16x32_bf16(w2hi, hf[mt][1], acc2[dt][mt], 0, 0, 0);
                acc2[dt][mt] = __builtin_amdgcn_mfma_f32_16x16x32_bf16(w2lo, hf[mt][0], acc2[dt][mt], 0, 0, 0);
            }
        }
    }

    // ---- Phase 3: epilogue, +b2, dwordx4 stores (lane holds 4 consecutive d)
    #pragma unroll
    for (int dt = 0; dt < 8; ++dt) {
        f32x4 b2v = *(const f32x4*)(b2 + dt * 16 + g * 4);
        #pragma unroll
        for (int mt = 0; mt < MT; ++mt) {
            f32x4 v = acc2[dt][mt] + b2v;
            int tok = tok_base + mt * 16 + li;
            *(f32x4*)(out + (size_t)tok * DIM + dt * 16 + g * 4) = v;
        }
    }
}

extern "C" void kernel_launch(void* const* d_in, const int* in_sizes, int n_in,
                              void* d_out, int out_size, void* d_ws, size_t ws_size,
                              hipStream_t stream) {
    const float* x  = (const float*)d_in[0];
    const float* w1 = (const float*)d_in[1];
    const float* w2 = (const float*)d_in[2];
    const float* b1 = (const float*)d_in[3];
    const float* b2 = (const float*)d_in[4];
    const float* wn = (const float*)d_in[5];
    const float* bn = (const float*)d_in[6];
    float* out = (float*)d_out;

    unsigned short* w1f = (unsigned short*)d_ws;
    unsigned short* w2f = w1f + 131072;

    prep_weights<<<1024, 256, 0, stream>>>(w1, w2, w1f, w2f);
    fused_mlp<<<2048, 256, 0, stream>>>(x, w1f, w2f, b1, b2, wn, bn, out);
}